// Round 12
// baseline (480.419 us; speedup 1.0000x reference)
//
#include <hip/hip_runtime.h>

// ---------------------------------------------------------------------------
// GraphSAGE x3 (sum aggr) + global mean pool.
// bf16 storage + MFMA 16x16x32 GEMMs (fp32 accum).
// Layer-3 gather: feature-chunked with HW XCD-id work claiming (chunk ==
// actual XCC_ID -> per-XCD L2 keeps its 3.2MB feature slice). Layer-2 gather
// kept as k_aggv control for within-round A/B.
// ---------------------------------------------------------------------------

typedef unsigned short u16;
typedef __attribute__((ext_vector_type(8))) short bf16x8;
typedef __attribute__((ext_vector_type(4))) float f32x4;

__device__ __forceinline__ u16 f2b(float f) {
    union { float f; unsigned u; } v; v.f = f;
    unsigned u = v.u;
    return (u16)((u + 0x7FFF + ((u >> 16) & 1)) >> 16);   // RNE
}
__device__ __forceinline__ float b2f(u16 h) {
    union { unsigned u; float f; } v; v.u = ((unsigned)h) << 16;
    return v.f;
}
__device__ __forceinline__ float blo(unsigned u) {
    union { unsigned u; float f; } v; v.u = u << 16;
    return v.f;
}
__device__ __forceinline__ float bhi(unsigned u) {
    union { unsigned u; float f; } v; v.u = u & 0xffff0000u;
    return v.f;
}

// ---------------- prep: x -> bf16, weights -> bf16 transposed [D][KP] ----------------
__global__ void k_prep(const float* __restrict__ x,
                       const float* __restrict__ W1l, const float* __restrict__ W1r,
                       const float* __restrict__ W2l, const float* __restrict__ W2r,
                       const float* __restrict__ W3l, const float* __restrict__ W3r,
                       u16* __restrict__ xb,
                       u16* __restrict__ wt1l, u16* __restrict__ wt1r,
                       u16* __restrict__ wt2l, u16* __restrict__ wt2r,
                       u16* __restrict__ wt3l, u16* __restrict__ wt3r, int N) {
    long idx = (long)blockIdx.x * 256 + threadIdx.x;
    long s0 = (long)N * 54;
    if (idx < s0) { xb[idx] = f2b(x[idx]); return; }
    idx -= s0;
    if (idx < 2 * 128 * 64) {
        u16* o = (idx < 128 * 64) ? wt1l : wt1r;
        const float* w = (idx < 128 * 64) ? W1l : W1r;
        long loc = idx % (128 * 64);
        int d = (int)(loc >> 6), k = (int)(loc & 63);
        o[loc] = (k < 54) ? f2b(w[(long)k * 128 + d]) : 0;
        return;
    }
    idx -= 2 * 128 * 64;
    if (idx < 2 * 256 * 128) {
        u16* o = (idx < 256 * 128) ? wt2l : wt2r;
        const float* w = (idx < 256 * 128) ? W2l : W2r;
        long loc = idx % (256 * 128);
        int d = (int)(loc >> 7), k = (int)(loc & 127);
        o[loc] = f2b(w[(long)k * 256 + d]);
        return;
    }
    idx -= 2 * 256 * 128;
    if (idx < 2 * 256 * 256) {
        u16* o = (idx < 256 * 256) ? wt3l : wt3r;
        const float* w = (idx < 256 * 256) ? W3l : W3r;
        long loc = idx % (256 * 256);
        int d = (int)(loc >> 8), k = (int)(loc & 255);
        o[loc] = f2b(w[(long)k * 256 + d]);
    }
}

// ---------------- CSR build ----------------
__global__ void k_count(const int* __restrict__ dst, int* __restrict__ cnt, int E) {
    int e = blockIdx.x * 256 + threadIdx.x;
    if (e < E) atomicAdd(&cnt[dst[e]], 1);
}

__global__ void k_bsum(const int* __restrict__ cnt, int* __restrict__ bsum, int N) {
    __shared__ int sm[256];
    int i = blockIdx.x * 256 + threadIdx.x;
    sm[threadIdx.x] = (i < N) ? cnt[i] : 0;
    __syncthreads();
    for (int off = 128; off > 0; off >>= 1) {
        if (threadIdx.x < off) sm[threadIdx.x] += sm[threadIdx.x + off];
        __syncthreads();
    }
    if (threadIdx.x == 0) bsum[blockIdx.x] = sm[0];
}

__global__ void k_bscan(const int* __restrict__ bsum, int* __restrict__ boff, int NB) {
    __shared__ int sm[256];
    int t = threadIdx.x;
    int v = (t < NB) ? bsum[t] : 0;
    sm[t] = v;
    __syncthreads();
    for (int off = 1; off < 256; off <<= 1) {
        int add = (t >= off) ? sm[t - off] : 0;
        __syncthreads();
        sm[t] += add;
        __syncthreads();
    }
    if (t < NB) boff[t] = sm[t] - v;  // exclusive
}

__global__ void k_scan(const int* __restrict__ cnt, const int* __restrict__ boff,
                       int* __restrict__ rowptr, int* __restrict__ wpos, int N, int E) {
    __shared__ int sm[256];
    int t = threadIdx.x;
    int i = blockIdx.x * 256 + t;
    int v = (i < N) ? cnt[i] : 0;
    sm[t] = v;
    __syncthreads();
    for (int off = 1; off < 256; off <<= 1) {
        int add = (t >= off) ? sm[t - off] : 0;
        __syncthreads();
        sm[t] += add;
        __syncthreads();
    }
    int ex = sm[t] - v + boff[blockIdx.x];
    if (i < N) { rowptr[i] = ex; wpos[i] = ex; }
    if (i == 0) rowptr[N] = E;
}

__global__ void k_fill(const int* __restrict__ src, const int* __restrict__ dst,
                       int* __restrict__ wpos, int* __restrict__ csr, int E) {
    int e = blockIdx.x * 256 + threadIdx.x;
    if (e < E) {
        int p = atomicAdd(&wpos[dst[e]], 1);
        csr[p] = src[e];
    }
}

// ---------------- aggregation, scalar variant (layer 1, D=54) ----------------
__global__ __launch_bounds__(256) void k_agg54(const u16* __restrict__ h,
                                               const int* __restrict__ rowptr,
                                               const int* __restrict__ csr,
                                               u16* __restrict__ agg, int n) {
    constexpr int D = 54;
    int w = threadIdx.x >> 6;
    int lane = threadIdx.x & 63;
    int i = blockIdx.x * 4 + w;
    if (i >= n) return;
    int b0 = rowptr[i], b1 = rowptr[i + 1];
    if (lane < D) {
        float a0 = 0.f;
        #pragma unroll 8
        for (int b = b0; b < b1; ++b) {
            int s = csr[b];
            a0 += b2f(h[(size_t)s * D + lane]);
        }
        agg[(size_t)i * D + lane] = f2b(a0);
    }
}

// ---------------- aggregation, multi-edge vector variant (control) ----------------
template <int D, int EPW>
__global__ __launch_bounds__(256) void k_aggv(const u16* __restrict__ h,
                                              const int* __restrict__ rowptr,
                                              const int* __restrict__ csr,
                                              u16* __restrict__ agg, int n) {
    constexpr int GRP = 64 / EPW;          // lanes per edge
    static_assert(D == GRP * 8, "geometry");
    int w = threadIdx.x >> 6;
    int lane = threadIdx.x & 63;
    int i = blockIdx.x * 4 + w;
    if (i >= n) return;
    int b0 = rowptr[i], b1 = rowptr[i + 1];
    int sub = lane / GRP;                  // which edge of the pack
    int dl = lane % GRP;                   // which 16B chunk of the row

    float a0 = 0.f, a1 = 0.f, a2 = 0.f, a3 = 0.f;
    float a4 = 0.f, a5 = 0.f, a6 = 0.f, a7 = 0.f;

    int b = b0;
    #pragma unroll 4
    for (; b + EPW <= b1; b += EPW) {
        int s = csr[b + sub];
        uint4 v = *reinterpret_cast<const uint4*>(h + (size_t)s * D + dl * 8);
        a0 += blo(v.x); a1 += bhi(v.x);
        a2 += blo(v.y); a3 += bhi(v.y);
        a4 += blo(v.z); a5 += bhi(v.z);
        a6 += blo(v.w); a7 += bhi(v.w);
    }
    int rem = b1 - b;
    if (sub < rem) {
        int s = csr[b + sub];
        uint4 v = *reinterpret_cast<const uint4*>(h + (size_t)s * D + dl * 8);
        a0 += blo(v.x); a1 += bhi(v.x);
        a2 += blo(v.y); a3 += bhi(v.y);
        a4 += blo(v.z); a5 += bhi(v.z);
        a6 += blo(v.w); a7 += bhi(v.w);
    }
    #pragma unroll
    for (int off = GRP; off < 64; off <<= 1) {
        a0 += __shfl_xor(a0, off, 64);
        a1 += __shfl_xor(a1, off, 64);
        a2 += __shfl_xor(a2, off, 64);
        a3 += __shfl_xor(a3, off, 64);
        a4 += __shfl_xor(a4, off, 64);
        a5 += __shfl_xor(a5, off, 64);
        a6 += __shfl_xor(a6, off, 64);
        a7 += __shfl_xor(a7, off, 64);
    }
    if (sub == 0) {
        uint4 o;
        o.x = ((unsigned)f2b(a0)) | (((unsigned)f2b(a1)) << 16);
        o.y = ((unsigned)f2b(a2)) | (((unsigned)f2b(a3)) << 16);
        o.z = ((unsigned)f2b(a4)) | (((unsigned)f2b(a5)) << 16);
        o.w = ((unsigned)f2b(a6)) | (((unsigned)f2b(a7)) << 16);
        *reinterpret_cast<uint4*>(agg + (size_t)i * D + dl * 8) = o;
    }
}

// ---------------- aggregation, XCD-chunked (treatment, layer 3) ----------------
// 8 feature chunks of CF=D/8. A block reads its REAL XCD id (HW_REG_XCC_ID)
// and claims a node-group for that chunk from per-chunk counters (steal
// fallback guarantees coverage; disjoint writes -> deterministic). Chunk c's
// N*CF*2B slice (3.2MB @ D=256) stays resident in XCD c's L2. csr/rowptr
// read nontemporal to avoid evicting the slice. 16B/lane loads.
template <int D, int CF>
__global__ __launch_bounds__(256) void k_aggx(const u16* __restrict__ h,
                                              const int* __restrict__ rowptr,
                                              const int* __restrict__ csr,
                                              u16* __restrict__ agg,
                                              int* __restrict__ ctr,
                                              int ngrp, int n) {
    static_assert(D == CF * 8, "8 chunks");
    constexpr int LPE = CF / 8;            // lanes per edge (16B each)
    constexpr int SLOTS = 64 / LPE;        // edges in flight per wave

    __shared__ int s_item[2];
    if (threadIdx.x == 0) {
        unsigned xcc;
        asm volatile("s_getreg_b32 %0, hwreg(HW_REG_XCC_ID)" : "=s"(xcc));
        int grp = -1, chunk = 0;
        #pragma unroll 1
        for (int t = 0; t < 8; ++t) {
            int c = (int)((xcc + t) & 7u);
            int g = atomicAdd(&ctr[c], 1);
            if (g < ngrp) { grp = g; chunk = c; break; }
        }
        s_item[0] = grp; s_item[1] = chunk;
    }
    __syncthreads();
    const int grp = s_item[0], chunk = s_item[1];
    if (grp < 0) return;

    const int w = threadIdx.x >> 6, lane = threadIdx.x & 63;
    const int slot = lane / LPE;
    const int fl = lane % LPE;
    const int col = chunk * CF + fl * 8;

    for (int t = 0; t < 8; ++t) {
        int node = grp * 32 + w * 8 + t;
        if (node >= n) continue;
        int b0 = __builtin_nontemporal_load(&rowptr[node]);
        int b1 = __builtin_nontemporal_load(&rowptr[node + 1]);
        float a0 = 0.f, a1 = 0.f, a2 = 0.f, a3 = 0.f;
        float a4 = 0.f, a5 = 0.f, a6 = 0.f, a7 = 0.f;
        int b = b0;
        for (; b + SLOTS <= b1; b += SLOTS) {
            int s = __builtin_nontemporal_load(&csr[b + slot]);
            uint4 v = *reinterpret_cast<const uint4*>(h + (size_t)s * D + col);
            a0 += blo(v.x); a1 += bhi(v.x);
            a2 += blo(v.y); a3 += bhi(v.y);
            a4 += blo(v.z); a5 += bhi(v.z);
            a6 += blo(v.w); a7 += bhi(v.w);
        }
        if (slot < b1 - b) {
            int s = __builtin_nontemporal_load(&csr[b + slot]);
            uint4 v = *reinterpret_cast<const uint4*>(h + (size_t)s * D + col);
            a0 += blo(v.x); a1 += bhi(v.x);
            a2 += blo(v.y); a3 += bhi(v.y);
            a4 += blo(v.z); a5 += bhi(v.z);
            a6 += blo(v.w); a7 += bhi(v.w);
        }
        #pragma unroll
        for (int off = LPE; off < 64; off <<= 1) {
            a0 += __shfl_xor(a0, off, 64);
            a1 += __shfl_xor(a1, off, 64);
            a2 += __shfl_xor(a2, off, 64);
            a3 += __shfl_xor(a3, off, 64);
            a4 += __shfl_xor(a4, off, 64);
            a5 += __shfl_xor(a5, off, 64);
            a6 += __shfl_xor(a6, off, 64);
            a7 += __shfl_xor(a7, off, 64);
        }
        if (slot == 0) {
            uint4 o;
            o.x = ((unsigned)f2b(a0)) | (((unsigned)f2b(a1)) << 16);
            o.y = ((unsigned)f2b(a2)) | (((unsigned)f2b(a3)) << 16);
            o.z = ((unsigned)f2b(a4)) | (((unsigned)f2b(a5)) << 16);
            o.w = ((unsigned)f2b(a6)) | (((unsigned)f2b(a7)) << 16);
            *reinterpret_cast<uint4*>(agg + (size_t)node * D + col) = o;
        }
    }
}

// ---------------- MFMA GEMM (layer 1): BN=DOUT=128, 256 thr ----------------
template <int KA, int KW, int DOUT, bool A16>
__global__ __launch_bounds__(256) void k_mgemm(const u16* __restrict__ A1,
                                               const u16* __restrict__ A2,
                                               const u16* __restrict__ Wt1,
                                               const u16* __restrict__ Wt2,
                                               const float* __restrict__ bias,
                                               u16* __restrict__ C, int N) {
    constexpr int BM = 128, BKP = 40;      // LDS rows padded to 80B -> 2-way only
    __shared__ u16 As[BM * BKP];
    __shared__ u16 Bs[BM * BKP];

    const int tid = threadIdx.x;
    const int w = tid >> 6, l = tid & 63;
    const int wr = w >> 1, wc = w & 1;     // wave grid 2x2
    const int lo = l & 15, hi = l >> 4;
    const int m0 = blockIdx.x * BM;
    const int n0 = 0;

    f32x4 acc[4][4];
    #pragma unroll
    for (int i = 0; i < 4; ++i)
        #pragma unroll
        for (int j = 0; j < 4; ++j) acc[i][j] = {0.f, 0.f, 0.f, 0.f};

    constexpr int KT = KW / 32;

    #pragma unroll
    for (int s = 0; s < 2; ++s) {
        const u16* __restrict__ Ap = s ? A2 : A1;
        const u16* __restrict__ Wp = s ? Wt2 : Wt1;
        for (int kt = 0; kt < KT; ++kt) {
            const int k0 = kt * 32;
            #pragma unroll
            for (int it = 0; it < 2; ++it) {
                int v = it * 256 + tid;
                int r = v >> 2, c = v & 3;
                uint4 val = *reinterpret_cast<const uint4*>(Wp + (size_t)(n0 + r) * KW + k0 + c * 8);
                *reinterpret_cast<uint4*>(&Bs[r * BKP + c * 8]) = val;
            }
            if constexpr (A16) {
                #pragma unroll
                for (int it = 0; it < 2; ++it) {
                    int v = it * 256 + tid;
                    int r = v >> 2, c = v & 3;
                    int m = m0 + r;
                    uint4 val = {0u, 0u, 0u, 0u};
                    if (m < N) val = *reinterpret_cast<const uint4*>(Ap + (size_t)m * KA + k0 + c * 8);
                    *reinterpret_cast<uint4*>(&As[r * BKP + c * 8]) = val;
                }
            } else {
                #pragma unroll
                for (int it = 0; it < 8; ++it) {
                    int v = it * 256 + tid;
                    int r = v >> 4, c = v & 15;
                    int m = m0 + r;
                    int k = k0 + c * 2;
                    unsigned val = 0;
                    if (m < N && k < KA)
                        val = *reinterpret_cast<const unsigned*>(Ap + (size_t)m * KA + k);
                    *reinterpret_cast<unsigned*>(&As[r * BKP + c * 2]) = val;
                }
            }
            __syncthreads();
            bf16x8 af[4], bf[4];
            #pragma unroll
            for (int f = 0; f < 4; ++f) {
                af[f] = *reinterpret_cast<const bf16x8*>(&Bs[(wc * 64 + f * 16 + lo) * BKP + hi * 8]);
                bf[f] = *reinterpret_cast<const bf16x8*>(&As[(wr * 64 + f * 16 + lo) * BKP + hi * 8]);
            }
            #pragma unroll
            for (int fm = 0; fm < 4; ++fm)
                #pragma unroll
                for (int fn = 0; fn < 4; ++fn)
                    acc[fm][fn] = __builtin_amdgcn_mfma_f32_16x16x32_bf16(af[fn], bf[fm], acc[fm][fn], 0, 0, 0);
            __syncthreads();
        }
    }
    #pragma unroll
    for (int fm = 0; fm < 4; ++fm) {
        int node = m0 + wr * 64 + fm * 16 + lo;
        if (node < N) {
            #pragma unroll
            for (int fn = 0; fn < 4; ++fn) {
                int fb = n0 + wc * 64 + fn * 16 + hi * 4;
                float4 bv = *reinterpret_cast<const float4*>(bias + fb);
                ushort4 o;
                o.x = f2b(fmaxf(acc[fm][fn][0] + bv.x, 0.f));
                o.y = f2b(fmaxf(acc[fm][fn][1] + bv.y, 0.f));
                o.z = f2b(fmaxf(acc[fm][fn][2] + bv.z, 0.f));
                o.w = f2b(fmaxf(acc[fm][fn][3] + bv.w, 0.f));
                *reinterpret_cast<ushort4*>(C + (size_t)node * DOUT + fb) = o;
            }
        }
    }
}

// ---------------- MFMA GEMM (layers 2,3): BN=DOUT, BM=64, 512 thr ----------------
template <int KA, int DOUT>
__global__ __launch_bounds__(512) void k_mgemm2(const u16* __restrict__ A1,
                                                const u16* __restrict__ A2,
                                                const u16* __restrict__ Wt1,
                                                const u16* __restrict__ Wt2,
                                                const float* __restrict__ bias,
                                                u16* __restrict__ C, int N) {
    constexpr int BM = 64, BKP = 40;
    constexpr int WCOL = DOUT / 4;         // 64
    constexpr int FN = WCOL / 16;          // 4
    __shared__ u16 As[BM * BKP];
    __shared__ u16 Bs[DOUT * BKP];

    const int tid = threadIdx.x;
    const int w = tid >> 6, lane = tid & 63;
    const int wr = w >> 2, wc = w & 3;     // 2x4 wave grid
    const int lo = lane & 15, hi = lane >> 4;
    const int m0 = blockIdx.x * BM;

    f32x4 acc[2][FN];
    #pragma unroll
    for (int i = 0; i < 2; ++i)
        #pragma unroll
        for (int j = 0; j < FN; ++j) acc[i][j] = {0.f, 0.f, 0.f, 0.f};

    constexpr int KT = KA / 32;

    #pragma unroll
    for (int s = 0; s < 2; ++s) {
        const u16* __restrict__ Ap = s ? A2 : A1;
        const u16* __restrict__ Wp = s ? Wt2 : Wt1;
        for (int kt = 0; kt < KT; ++kt) {
            const int k0 = kt * 32;
            #pragma unroll
            for (int it = 0; it < DOUT * 32 / 8 / 512; ++it) {
                int v = it * 512 + tid;
                int r = v >> 2, c = v & 3;
                uint4 val = *reinterpret_cast<const uint4*>(Wp + (size_t)r * KA + k0 + c * 8);
                *reinterpret_cast<uint4*>(&Bs[r * BKP + c * 8]) = val;
            }
            if (tid < 256) {
                int r = tid >> 2, c = tid & 3;
                int m = m0 + r;
                uint4 val = {0u, 0u, 0u, 0u};
                if (m < N) val = *reinterpret_cast<const uint4*>(Ap + (size_t)m * KA + k0 + c * 8);
                *reinterpret_cast<uint4*>(&As[r * BKP + c * 8]) = val;
            }
            __syncthreads();
            bf16x8 bfr[2];
            #pragma unroll
            for (int fm = 0; fm < 2; ++fm)
                bfr[fm] = *reinterpret_cast<const bf16x8*>(&As[(wr * 32 + fm * 16 + lo) * BKP + hi * 8]);
            #pragma unroll
            for (int fn = 0; fn < FN; ++fn) {
                bf16x8 af = *reinterpret_cast<const bf16x8*>(&Bs[(wc * WCOL + fn * 16 + lo) * BKP + hi * 8]);
                #pragma unroll
                for (int fm = 0; fm < 2; ++fm)
                    acc[fm][fn] = __builtin_amdgcn_mfma_f32_16x16x32_bf16(af, bfr[fm], acc[fm][fn], 0, 0, 0);
            }
            __syncthreads();
        }
    }
    #pragma unroll
    for (int fm = 0; fm < 2; ++fm) {
        int node = m0 + wr * 32 + fm * 16 + lo;
        if (node < N) {
            #pragma unroll
            for (int fn = 0; fn < FN; ++fn) {
                int fb = wc * WCOL + fn * 16 + hi * 4;
                float4 bv = *reinterpret_cast<const float4*>(bias + fb);
                ushort4 o;
                o.x = f2b(fmaxf(acc[fm][fn][0] + bv.x, 0.f));
                o.y = f2b(fmaxf(acc[fm][fn][1] + bv.y, 0.f));
                o.z = f2b(fmaxf(acc[fm][fn][2] + bv.z, 0.f));
                o.w = f2b(fmaxf(acc[fm][fn][3] + bv.w, 0.f));
                *reinterpret_cast<ushort4*>(C + (size_t)node * DOUT + fb) = o;
            }
        }
    }
}

// ---------------- global mean pool (bf16 in, fp32 out) ----------------
template <int ROWS>
__global__ void k_pool(const u16* __restrict__ h3, const int* __restrict__ batch,
                       float* __restrict__ outsum, int* __restrict__ cnt, int N) {
    int r0 = blockIdx.x * ROWS;
    int r1 = min(r0 + ROWS, N);
    if (r0 >= N) return;
    int d = threadIdx.x;
    int cur = batch[r0];
    float s = 0.f;
    int c = 0;
    for (int i = r0; i < r1; ++i) {
        int g = batch[i];  // uniform across block
        if (g != cur) {
            atomicAdd(&outsum[cur * 256 + d], s);
            if (d == 0) atomicAdd(&cnt[cur], c);
            s = 0.f; c = 0; cur = g;
        }
        s += b2f(h3[(size_t)i * 256 + d]);
        c++;
    }
    atomicAdd(&outsum[cur * 256 + d], s);
    if (d == 0) atomicAdd(&cnt[cur], c);
}

__global__ void k_div(float* __restrict__ out, const int* __restrict__ cnt, int total) {
    int idx = blockIdx.x * 256 + threadIdx.x;
    if (idx < total) {
        float c = fmaxf((float)cnt[idx >> 8], 1.0f);
        out[idx] = out[idx] / c;
    }
}

// ---------------------------------------------------------------------------
extern "C" void kernel_launch(void* const* d_in, const int* in_sizes, int n_in,
                              void* d_out, int out_size, void* d_ws, size_t ws_size,
                              hipStream_t stream) {
    const float* x   = (const float*)d_in[0];
    const int* ei    = (const int*)d_in[1];
    const int* batch = (const int*)d_in[2];
    const float* W1l = (const float*)d_in[3];
    const float* b1  = (const float*)d_in[4];
    const float* W1r = (const float*)d_in[5];
    const float* W2l = (const float*)d_in[6];
    const float* b2  = (const float*)d_in[7];
    const float* W2r = (const float*)d_in[8];
    const float* W3l = (const float*)d_in[9];
    const float* b3  = (const float*)d_in[10];
    const float* W3r = (const float*)d_in[11];

    const int N = in_sizes[0] / 54;
    const int E = in_sizes[1] / 2;
    const int* src = ei;
    const int* dst = ei + E;

    // workspace layout (bf16 = u16)
    u16* xb   = (u16*)d_ws;                       // N*54
    u16* bufA = xb + (size_t)N * 54;              // agg out, N*256 max
    u16* buf1 = bufA + (size_t)N * 256;           // h1 / h3
    u16* buf2 = buf1 + (size_t)N * 256;           // h2
    u16* wt1l = buf2 + (size_t)N * 256;           // [128][64]
    u16* wt1r = wt1l + 128 * 64;
    u16* wt2l = wt1r + 128 * 64;                  // [256][128]
    u16* wt2r = wt2l + 256 * 128;
    u16* wt3l = wt2r + 256 * 128;                 // [256][256]
    u16* wt3r = wt3l + 256 * 256;
    int* ip = (int*)(wt3r + 256 * 256);
    int* cntdeg  = ip; ip += N;
    int* rowptr  = ip; ip += N + 1;
    int* wpos    = ip; ip += N + 1;
    int* bsum    = ip; ip += 256;
    int* boff    = ip; ip += 256;
    int* cntpool = ip; ip += 128;
    int* ctrx    = ip; ip += 8;                   // chunk claim counters (layer 3)
    int* csr     = ip;                            // E ints

    hipMemsetAsync(cntdeg, 0, (size_t)N * sizeof(int), stream);
    hipMemsetAsync(d_out, 0, (size_t)out_size * sizeof(float), stream);
    hipMemsetAsync(cntpool, 0, 128 * sizeof(int), stream);
    hipMemsetAsync(ctrx, 0, 8 * sizeof(int), stream);

    const int NB = (N + 255) / 256;
    const int EB = (E + 255) / 256;

    // prep: bf16 conversions + weight transposes
    {
        long total = (long)N * 54 + 2L * 128 * 64 + 2L * 256 * 128 + 2L * 256 * 256;
        int g = (int)((total + 255) / 256);
        k_prep<<<g, 256, 0, stream>>>(x, W1l, W1r, W2l, W2r, W3l, W3r,
                                      xb, wt1l, wt1r, wt2l, wt2r, wt3l, wt3r, N);
    }

    // CSR build
    k_count<<<EB, 256, 0, stream>>>(dst, cntdeg, E);
    k_bsum<<<NB, 256, 0, stream>>>(cntdeg, bsum, N);
    k_bscan<<<1, 256, 0, stream>>>(bsum, boff, NB);
    k_scan<<<NB, 256, 0, stream>>>(cntdeg, boff, rowptr, wpos, N, E);
    k_fill<<<EB, 256, 0, stream>>>(src, dst, wpos, csr, E);

    const int AGB = (N + 3) / 4;
    const int GX = (N + 127) / 128;    // layer-1 GEMM (BM=128)
    const int GX2 = (N + 63) / 64;     // layer-2/3 GEMM (BM=64)

    // layer 1: 54 -> 128
    k_agg54<<<AGB, 256, 0, stream>>>(xb, rowptr, csr, bufA, N);
    k_mgemm<54, 64, 128, false><<<GX, 256, 0, stream>>>(bufA, xb, wt1l, wt1r, b1, buf1, N);
    // layer 2: 128 -> 256  (control: k_aggv)
    k_aggv<128, 4><<<AGB, 256, 0, stream>>>(buf1, rowptr, csr, bufA, N);
    k_mgemm2<128, 256><<<GX2, 512, 0, stream>>>(bufA, buf1, wt2l, wt2r, b2, buf2, N);
    // layer 3: 256 -> 256  (treatment: XCD-chunked gather)
    {
        int ngrp = (N + 31) / 32;
        k_aggx<256, 32><<<8 * ngrp, 256, 0, stream>>>(buf2, rowptr, csr, bufA, ctrx, ngrp, N);
    }
    k_mgemm2<256, 256><<<GX2, 512, 0, stream>>>(bufA, buf2, wt3l, wt3r, b3, buf1, N);

    // global mean pool
    k_pool<32><<<(N + 31) / 32, 256, 0, stream>>>(buf1, batch, (float*)d_out, cntpool, N);
    k_div<<<(out_size + 255) / 256, 256, 0, stream>>>((float*)d_out, cntpool, out_size);
}

// Round 13
// 304.172 us; speedup vs baseline: 1.5794x; 1.5794x over previous
//
#include <hip/hip_runtime.h>

// ---------------------------------------------------------------------------
// GraphSAGE x3 (sum aggr) + global mean pool.
// bf16 storage + MFMA 16x16x32 GEMMs (fp32 accum).
// R11 structure (best, 343us) + padded x rows (128B-aligned layer-1 gather).
// Gather locality schemes falsified (R10/R12); fusion falsified (R8/R9).
// ---------------------------------------------------------------------------

typedef unsigned short u16;
typedef __attribute__((ext_vector_type(8))) short bf16x8;
typedef __attribute__((ext_vector_type(4))) float f32x4;

__device__ __forceinline__ u16 f2b(float f) {
    union { float f; unsigned u; } v; v.f = f;
    unsigned u = v.u;
    return (u16)((u + 0x7FFF + ((u >> 16) & 1)) >> 16);   // RNE
}
__device__ __forceinline__ float b2f(u16 h) {
    union { unsigned u; float f; } v; v.u = ((unsigned)h) << 16;
    return v.f;
}
__device__ __forceinline__ float blo(unsigned u) {
    union { unsigned u; float f; } v; v.u = u << 16;
    return v.f;
}
__device__ __forceinline__ float bhi(unsigned u) {
    union { unsigned u; float f; } v; v.u = u & 0xffff0000u;
    return v.f;
}

// ---------------- prep: x -> bf16 [N][64] zero-padded, weights -> bf16 [D][KP],
// ---------------- plus fused degree histogram ----------------
__global__ void k_prep(const float* __restrict__ x,
                       const float* __restrict__ W1l, const float* __restrict__ W1r,
                       const float* __restrict__ W2l, const float* __restrict__ W2r,
                       const float* __restrict__ W3l, const float* __restrict__ W3r,
                       const int* __restrict__ dst, int* __restrict__ cntdeg,
                       u16* __restrict__ xb,
                       u16* __restrict__ wt1l, u16* __restrict__ wt1r,
                       u16* __restrict__ wt2l, u16* __restrict__ wt2r,
                       u16* __restrict__ wt3l, u16* __restrict__ wt3r,
                       int N, int E) {
    long idx = (long)blockIdx.x * 256 + threadIdx.x;
    long s0 = (long)N * 64;
    if (idx < s0) {
        int row = (int)(idx >> 6), k = (int)(idx & 63);
        xb[idx] = (k < 54) ? f2b(x[(size_t)row * 54 + k]) : 0;
        return;
    }
    idx -= s0;
    if (idx < 2 * 128 * 64) {
        u16* o = (idx < 128 * 64) ? wt1l : wt1r;
        const float* w = (idx < 128 * 64) ? W1l : W1r;
        long loc = idx % (128 * 64);
        int d = (int)(loc >> 6), k = (int)(loc & 63);
        o[loc] = (k < 54) ? f2b(w[(long)k * 128 + d]) : 0;
        return;
    }
    idx -= 2 * 128 * 64;
    if (idx < 2 * 256 * 128) {
        u16* o = (idx < 256 * 128) ? wt2l : wt2r;
        const float* w = (idx < 256 * 128) ? W2l : W2r;
        long loc = idx % (256 * 128);
        int d = (int)(loc >> 7), k = (int)(loc & 127);
        o[loc] = f2b(w[(long)k * 256 + d]);
        return;
    }
    idx -= 2 * 256 * 128;
    if (idx < 2 * 256 * 256) {
        u16* o = (idx < 256 * 256) ? wt3l : wt3r;
        const float* w = (idx < 256 * 256) ? W3l : W3r;
        long loc = idx % (256 * 256);
        int d = (int)(loc >> 8), k = (int)(loc & 255);
        o[loc] = f2b(w[(long)k * 256 + d]);
        return;
    }
    idx -= 2 * 256 * 256;
    if (idx < E) atomicAdd(&cntdeg[dst[idx]], 1);   // fused k_count
}

// ---------------- CSR build ----------------
__global__ void k_bsum(const int* __restrict__ cnt, int* __restrict__ bsum, int N) {
    __shared__ int sm[256];
    int i = blockIdx.x * 256 + threadIdx.x;
    sm[threadIdx.x] = (i < N) ? cnt[i] : 0;
    __syncthreads();
    for (int off = 128; off > 0; off >>= 1) {
        if (threadIdx.x < off) sm[threadIdx.x] += sm[threadIdx.x + off];
        __syncthreads();
    }
    if (threadIdx.x == 0) bsum[blockIdx.x] = sm[0];
}

__global__ void k_bscan(const int* __restrict__ bsum, int* __restrict__ boff, int NB) {
    __shared__ int sm[256];
    int t = threadIdx.x;
    int v = (t < NB) ? bsum[t] : 0;
    sm[t] = v;
    __syncthreads();
    for (int off = 1; off < 256; off <<= 1) {
        int add = (t >= off) ? sm[t - off] : 0;
        __syncthreads();
        sm[t] += add;
        __syncthreads();
    }
    if (t < NB) boff[t] = sm[t] - v;  // exclusive
}

__global__ void k_scan(const int* __restrict__ cnt, const int* __restrict__ boff,
                       int* __restrict__ rowptr, int* __restrict__ wpos, int N, int E) {
    __shared__ int sm[256];
    int t = threadIdx.x;
    int i = blockIdx.x * 256 + t;
    int v = (i < N) ? cnt[i] : 0;
    sm[t] = v;
    __syncthreads();
    for (int off = 1; off < 256; off <<= 1) {
        int add = (t >= off) ? sm[t - off] : 0;
        __syncthreads();
        sm[t] += add;
        __syncthreads();
    }
    int ex = sm[t] - v + boff[blockIdx.x];
    if (i < N) { rowptr[i] = ex; wpos[i] = ex; }
    if (i == 0) rowptr[N] = E;
}

__global__ void k_fill(const int* __restrict__ src, const int* __restrict__ dst,
                       int* __restrict__ wpos, int* __restrict__ csr, int E) {
    int e = blockIdx.x * 256 + threadIdx.x;
    if (e < E) {
        int p = atomicAdd(&wpos[dst[e]], 1);
        csr[p] = src[e];
    }
}

// ---------------- aggregation, multi-edge vector variant ----------------
// One wave per node. Each iteration processes EPW edges: lanes split into EPW
// groups of GRP=64/EPW lanes; each lane loads 16B (8 bf16) of its edge's row.
template <int D, int EPW>
__global__ __launch_bounds__(256) void k_aggv(const u16* __restrict__ h,
                                              const int* __restrict__ rowptr,
                                              const int* __restrict__ csr,
                                              u16* __restrict__ agg, int n) {
    constexpr int GRP = 64 / EPW;          // lanes per edge
    static_assert(D == GRP * 8, "geometry");
    int w = threadIdx.x >> 6;
    int lane = threadIdx.x & 63;
    int i = blockIdx.x * 4 + w;
    if (i >= n) return;
    int b0 = rowptr[i], b1 = rowptr[i + 1];
    int sub = lane / GRP;                  // which edge of the pack
    int dl = lane % GRP;                   // which 16B chunk of the row

    float a0 = 0.f, a1 = 0.f, a2 = 0.f, a3 = 0.f;
    float a4 = 0.f, a5 = 0.f, a6 = 0.f, a7 = 0.f;

    int b = b0;
    #pragma unroll 4
    for (; b + EPW <= b1; b += EPW) {
        int s = csr[b + sub];
        uint4 v = *reinterpret_cast<const uint4*>(h + (size_t)s * D + dl * 8);
        a0 += blo(v.x); a1 += bhi(v.x);
        a2 += blo(v.y); a3 += bhi(v.y);
        a4 += blo(v.z); a5 += bhi(v.z);
        a6 += blo(v.w); a7 += bhi(v.w);
    }
    int rem = b1 - b;
    if (sub < rem) {
        int s = csr[b + sub];
        uint4 v = *reinterpret_cast<const uint4*>(h + (size_t)s * D + dl * 8);
        a0 += blo(v.x); a1 += bhi(v.x);
        a2 += blo(v.y); a3 += bhi(v.y);
        a4 += blo(v.z); a5 += bhi(v.z);
        a6 += blo(v.w); a7 += bhi(v.w);
    }
    #pragma unroll
    for (int off = GRP; off < 64; off <<= 1) {
        a0 += __shfl_xor(a0, off, 64);
        a1 += __shfl_xor(a1, off, 64);
        a2 += __shfl_xor(a2, off, 64);
        a3 += __shfl_xor(a3, off, 64);
        a4 += __shfl_xor(a4, off, 64);
        a5 += __shfl_xor(a5, off, 64);
        a6 += __shfl_xor(a6, off, 64);
        a7 += __shfl_xor(a7, off, 64);
    }
    if (sub == 0) {
        uint4 o;
        o.x = ((unsigned)f2b(a0)) | (((unsigned)f2b(a1)) << 16);
        o.y = ((unsigned)f2b(a2)) | (((unsigned)f2b(a3)) << 16);
        o.z = ((unsigned)f2b(a4)) | (((unsigned)f2b(a5)) << 16);
        o.w = ((unsigned)f2b(a6)) | (((unsigned)f2b(a7)) << 16);
        *reinterpret_cast<uint4*>(agg + (size_t)i * D + dl * 8) = o;
    }
}

// ---------------- MFMA GEMM (layer 1): BN=DOUT=128, 256 thr ----------------
template <int KA, int KW, int DOUT, bool A16>
__global__ __launch_bounds__(256) void k_mgemm(const u16* __restrict__ A1,
                                               const u16* __restrict__ A2,
                                               const u16* __restrict__ Wt1,
                                               const u16* __restrict__ Wt2,
                                               const float* __restrict__ bias,
                                               u16* __restrict__ C, int N) {
    constexpr int BM = 128, BKP = 40;      // LDS rows padded to 80B -> 2-way only
    __shared__ u16 As[BM * BKP];
    __shared__ u16 Bs[BM * BKP];

    const int tid = threadIdx.x;
    const int w = tid >> 6, l = tid & 63;
    const int wr = w >> 1, wc = w & 1;     // wave grid 2x2
    const int lo = l & 15, hi = l >> 4;
    const int m0 = blockIdx.x * BM;
    const int n0 = 0;

    f32x4 acc[4][4];
    #pragma unroll
    for (int i = 0; i < 4; ++i)
        #pragma unroll
        for (int j = 0; j < 4; ++j) acc[i][j] = {0.f, 0.f, 0.f, 0.f};

    constexpr int KT = KW / 32;

    #pragma unroll
    for (int s = 0; s < 2; ++s) {
        const u16* __restrict__ Ap = s ? A2 : A1;
        const u16* __restrict__ Wp = s ? Wt2 : Wt1;
        for (int kt = 0; kt < KT; ++kt) {
            const int k0 = kt * 32;
            #pragma unroll
            for (int it = 0; it < 2; ++it) {
                int v = it * 256 + tid;
                int r = v >> 2, c = v & 3;
                uint4 val = *reinterpret_cast<const uint4*>(Wp + (size_t)(n0 + r) * KW + k0 + c * 8);
                *reinterpret_cast<uint4*>(&Bs[r * BKP + c * 8]) = val;
            }
            if constexpr (A16) {
                #pragma unroll
                for (int it = 0; it < 2; ++it) {
                    int v = it * 256 + tid;
                    int r = v >> 2, c = v & 3;
                    int m = m0 + r;
                    uint4 val = {0u, 0u, 0u, 0u};
                    if (m < N) val = *reinterpret_cast<const uint4*>(Ap + (size_t)m * KA + k0 + c * 8);
                    *reinterpret_cast<uint4*>(&As[r * BKP + c * 8]) = val;
                }
            } else {
                #pragma unroll
                for (int it = 0; it < 8; ++it) {
                    int v = it * 256 + tid;
                    int r = v >> 4, c = v & 15;
                    int m = m0 + r;
                    int k = k0 + c * 2;
                    unsigned val = 0;
                    if (m < N && k < KA)
                        val = *reinterpret_cast<const unsigned*>(Ap + (size_t)m * KA + k);
                    *reinterpret_cast<unsigned*>(&As[r * BKP + c * 2]) = val;
                }
            }
            __syncthreads();
            bf16x8 af[4], bf[4];
            #pragma unroll
            for (int f = 0; f < 4; ++f) {
                af[f] = *reinterpret_cast<const bf16x8*>(&Bs[(wc * 64 + f * 16 + lo) * BKP + hi * 8]);
                bf[f] = *reinterpret_cast<const bf16x8*>(&As[(wr * 64 + f * 16 + lo) * BKP + hi * 8]);
            }
            #pragma unroll
            for (int fm = 0; fm < 4; ++fm)
                #pragma unroll
                for (int fn = 0; fn < 4; ++fn)
                    acc[fm][fn] = __builtin_amdgcn_mfma_f32_16x16x32_bf16(af[fn], bf[fm], acc[fm][fn], 0, 0, 0);
            __syncthreads();
        }
    }
    #pragma unroll
    for (int fm = 0; fm < 4; ++fm) {
        int node = m0 + wr * 64 + fm * 16 + lo;
        if (node < N) {
            #pragma unroll
            for (int fn = 0; fn < 4; ++fn) {
                int fb = n0 + wc * 64 + fn * 16 + hi * 4;
                float4 bv = *reinterpret_cast<const float4*>(bias + fb);
                ushort4 o;
                o.x = f2b(fmaxf(acc[fm][fn][0] + bv.x, 0.f));
                o.y = f2b(fmaxf(acc[fm][fn][1] + bv.y, 0.f));
                o.z = f2b(fmaxf(acc[fm][fn][2] + bv.z, 0.f));
                o.w = f2b(fmaxf(acc[fm][fn][3] + bv.w, 0.f));
                *reinterpret_cast<ushort4*>(C + (size_t)node * DOUT + fb) = o;
            }
        }
    }
}

// ---------------- MFMA GEMM (layers 2,3): BN=DOUT, BM=64, 512 thr ----------------
template <int KA, int DOUT>
__global__ __launch_bounds__(512) void k_mgemm2(const u16* __restrict__ A1,
                                                const u16* __restrict__ A2,
                                                const u16* __restrict__ Wt1,
                                                const u16* __restrict__ Wt2,
                                                const float* __restrict__ bias,
                                                u16* __restrict__ C, int N) {
    constexpr int BM = 64, BKP = 40;
    constexpr int WCOL = DOUT / 4;         // 64
    constexpr int FN = WCOL / 16;          // 4
    __shared__ u16 As[BM * BKP];
    __shared__ u16 Bs[DOUT * BKP];

    const int tid = threadIdx.x;
    const int w = tid >> 6, lane = tid & 63;
    const int wr = w >> 2, wc = w & 3;     // 2x4 wave grid
    const int lo = lane & 15, hi = lane >> 4;
    const int m0 = blockIdx.x * BM;

    f32x4 acc[2][FN];
    #pragma unroll
    for (int i = 0; i < 2; ++i)
        #pragma unroll
        for (int j = 0; j < FN; ++j) acc[i][j] = {0.f, 0.f, 0.f, 0.f};

    constexpr int KT = KA / 32;

    #pragma unroll
    for (int s = 0; s < 2; ++s) {
        const u16* __restrict__ Ap = s ? A2 : A1;
        const u16* __restrict__ Wp = s ? Wt2 : Wt1;
        for (int kt = 0; kt < KT; ++kt) {
            const int k0 = kt * 32;
            #pragma unroll
            for (int it = 0; it < DOUT * 32 / 8 / 512; ++it) {
                int v = it * 512 + tid;
                int r = v >> 2, c = v & 3;
                uint4 val = *reinterpret_cast<const uint4*>(Wp + (size_t)r * KA + k0 + c * 8);
                *reinterpret_cast<uint4*>(&Bs[r * BKP + c * 8]) = val;
            }
            if (tid < 256) {
                int r = tid >> 2, c = tid & 3;
                int m = m0 + r;
                uint4 val = {0u, 0u, 0u, 0u};
                if (m < N) val = *reinterpret_cast<const uint4*>(Ap + (size_t)m * KA + k0 + c * 8);
                *reinterpret_cast<uint4*>(&As[r * BKP + c * 8]) = val;
            }
            __syncthreads();
            bf16x8 bfr[2];
            #pragma unroll
            for (int fm = 0; fm < 2; ++fm)
                bfr[fm] = *reinterpret_cast<const bf16x8*>(&As[(wr * 32 + fm * 16 + lo) * BKP + hi * 8]);
            #pragma unroll
            for (int fn = 0; fn < FN; ++fn) {
                bf16x8 af = *reinterpret_cast<const bf16x8*>(&Bs[(wc * WCOL + fn * 16 + lo) * BKP + hi * 8]);
                #pragma unroll
                for (int fm = 0; fm < 2; ++fm)
                    acc[fm][fn] = __builtin_amdgcn_mfma_f32_16x16x32_bf16(af, bfr[fm], acc[fm][fn], 0, 0, 0);
            }
            __syncthreads();
        }
    }
    #pragma unroll
    for (int fm = 0; fm < 2; ++fm) {
        int node = m0 + wr * 32 + fm * 16 + lo;
        if (node < N) {
            #pragma unroll
            for (int fn = 0; fn < FN; ++fn) {
                int fb = wc * WCOL + fn * 16 + hi * 4;
                float4 bv = *reinterpret_cast<const float4*>(bias + fb);
                ushort4 o;
                o.x = f2b(fmaxf(acc[fm][fn][0] + bv.x, 0.f));
                o.y = f2b(fmaxf(acc[fm][fn][1] + bv.y, 0.f));
                o.z = f2b(fmaxf(acc[fm][fn][2] + bv.z, 0.f));
                o.w = f2b(fmaxf(acc[fm][fn][3] + bv.w, 0.f));
                *reinterpret_cast<ushort4*>(C + (size_t)node * DOUT + fb) = o;
            }
        }
    }
}

// ---------------- global mean pool (bf16 in, fp32 out) ----------------
template <int ROWS>
__global__ void k_pool(const u16* __restrict__ h3, const int* __restrict__ batch,
                       float* __restrict__ outsum, int* __restrict__ cnt, int N) {
    int r0 = blockIdx.x * ROWS;
    int r1 = min(r0 + ROWS, N);
    if (r0 >= N) return;
    int d = threadIdx.x;
    int cur = batch[r0];
    float s = 0.f;
    int c = 0;
    for (int i = r0; i < r1; ++i) {
        int g = batch[i];  // uniform across block
        if (g != cur) {
            atomicAdd(&outsum[cur * 256 + d], s);
            if (d == 0) atomicAdd(&cnt[cur], c);
            s = 0.f; c = 0; cur = g;
        }
        s += b2f(h3[(size_t)i * 256 + d]);
        c++;
    }
    atomicAdd(&outsum[cur * 256 + d], s);
    if (d == 0) atomicAdd(&cnt[cur], c);
}

__global__ void k_div(float* __restrict__ out, const int* __restrict__ cnt, int total) {
    int idx = blockIdx.x * 256 + threadIdx.x;
    if (idx < total) {
        float c = fmaxf((float)cnt[idx >> 8], 1.0f);
        out[idx] = out[idx] / c;
    }
}

// ---------------------------------------------------------------------------
extern "C" void kernel_launch(void* const* d_in, const int* in_sizes, int n_in,
                              void* d_out, int out_size, void* d_ws, size_t ws_size,
                              hipStream_t stream) {
    const float* x   = (const float*)d_in[0];
    const int* ei    = (const int*)d_in[1];
    const int* batch = (const int*)d_in[2];
    const float* W1l = (const float*)d_in[3];
    const float* b1  = (const float*)d_in[4];
    const float* W1r = (const float*)d_in[5];
    const float* W2l = (const float*)d_in[6];
    const float* b2  = (const float*)d_in[7];
    const float* W2r = (const float*)d_in[8];
    const float* W3l = (const float*)d_in[9];
    const float* b3  = (const float*)d_in[10];
    const float* W3r = (const float*)d_in[11];

    const int N = in_sizes[0] / 54;
    const int E = in_sizes[1] / 2;
    const int* src = ei;
    const int* dst = ei + E;

    // workspace layout (bf16 = u16)
    u16* xb   = (u16*)d_ws;                       // N*64 (padded rows)
    u16* bufA = xb + (size_t)N * 64;              // agg out, N*256 max
    u16* buf1 = bufA + (size_t)N * 256;           // h1 / h3
    u16* buf2 = buf1 + (size_t)N * 256;           // h2
    u16* wt1l = buf2 + (size_t)N * 256;           // [128][64]
    u16* wt1r = wt1l + 128 * 64;
    u16* wt2l = wt1r + 128 * 64;                  // [256][128]
    u16* wt2r = wt2l + 256 * 128;
    u16* wt3l = wt2r + 256 * 128;                 // [256][256]
    u16* wt3r = wt3l + 256 * 256;
    int* ip = (int*)(wt3r + 256 * 256);
    int* cntdeg  = ip; ip += N;
    int* rowptr  = ip; ip += N + 1;
    int* wpos    = ip; ip += N + 1;
    int* bsum    = ip; ip += 256;
    int* boff    = ip; ip += 256;
    int* cntpool = ip; ip += 128;
    int* csr     = ip;                            // E ints

    hipMemsetAsync(cntdeg, 0, (size_t)N * sizeof(int), stream);
    hipMemsetAsync(d_out, 0, (size_t)out_size * sizeof(float), stream);
    hipMemsetAsync(cntpool, 0, 128 * sizeof(int), stream);

    const int NB = (N + 255) / 256;
    const int EB = (E + 255) / 256;

    // prep: bf16 conversions + weight transposes + degree count (fused)
    {
        long total = (long)N * 64 + 2L * 128 * 64 + 2L * 256 * 128 + 2L * 256 * 256 + E;
        int g = (int)((total + 255) / 256);
        k_prep<<<g, 256, 0, stream>>>(x, W1l, W1r, W2l, W2r, W3l, W3r,
                                      dst, cntdeg,
                                      xb, wt1l, wt1r, wt2l, wt2r, wt3l, wt3r, N, E);
    }

    // CSR build
    k_bsum<<<NB, 256, 0, stream>>>(cntdeg, bsum, N);
    k_bscan<<<1, 256, 0, stream>>>(bsum, boff, NB);
    k_scan<<<NB, 256, 0, stream>>>(cntdeg, boff, rowptr, wpos, N, E);
    k_fill<<<EB, 256, 0, stream>>>(src, dst, wpos, csr, E);

    const int AGB = (N + 3) / 4;
    const int GX = (N + 127) / 128;    // layer-1 GEMM (BM=128)
    const int GX2 = (N + 63) / 64;     // layer-2/3 GEMM (BM=64)

    // layer 1: 54(padded 64) -> 128
    k_aggv<64, 8><<<AGB, 256, 0, stream>>>(xb, rowptr, csr, bufA, N);
    k_mgemm<64, 64, 128, true><<<GX, 256, 0, stream>>>(bufA, xb, wt1l, wt1r, b1, buf1, N);
    // layer 2: 128 -> 256
    k_aggv<128, 4><<<AGB, 256, 0, stream>>>(buf1, rowptr, csr, bufA, N);
    k_mgemm2<128, 256><<<GX2, 512, 0, stream>>>(bufA, buf1, wt2l, wt2r, b2, buf2, N);
    // layer 3: 256 -> 256
    k_aggv<256, 2><<<AGB, 256, 0, stream>>>(buf2, rowptr, csr, bufA, N);
    k_mgemm2<256, 256><<<GX2, 512, 0, stream>>>(bufA, buf2, wt3l, wt3r, b3, buf1, N);

    // global mean pool
    k_pool<32><<<(N + 31) / 32, 256, 0, stream>>>(buf1, batch, (float*)d_out, cntpool, N);
    k_div<<<(out_size + 255) / 256, 256, 0, stream>>>((float*)d_out, cntpool, out_size);
}